// Round 18
// baseline (912.693 us; speedup 1.0000x reference)
//
#include <hip/hip_runtime.h>
#include <hip/hip_bf16.h>
#include <math.h>

#define N_NODES 65536
#define HW      65536
#define NE      524288
#define NC      (N_NODES * 64)

typedef __bf16 bf16x8 __attribute__((ext_vector_type(8)));
typedef float  f32x4  __attribute__((ext_vector_type(4)));
typedef float  f32x2  __attribute__((ext_vector_type(2)));
typedef int    i32x4  __attribute__((ext_vector_type(4)));
typedef unsigned int uint2v __attribute__((ext_vector_type(2)));

static __device__ __forceinline__ f32x4 mfma16(bf16x8 a, bf16x8 b, f32x4 c) {
    return __builtin_amdgcn_mfma_f32_16x16x32_bf16(a, b, c, 0, 0, 0);
}

static __device__ __forceinline__ unsigned short f2bs(float f) {
    return __builtin_bit_cast(unsigned short, __float2bfloat16(f));
}

// ---------------- CSR build ----------------
__global__ void k_hist(const int* __restrict__ dstA, int* __restrict__ cnt) {
    int e = blockIdx.x * 256 + threadIdx.x;
    if (e < NE) atomicAdd(&cnt[dstA[e]], 1);
}

__global__ void k_scan(const int* __restrict__ cnt, int* __restrict__ off) {
    __shared__ int sums[1024];
    int t = threadIdx.x;
    int base = t * 64;
    int s = 0;
    for (int i = 0; i < 64; ++i) s += cnt[base + i];
    sums[t] = s;
    __syncthreads();
    for (int d = 1; d < 1024; d <<= 1) {
        int v = (t >= d) ? sums[t - d] : 0;
        __syncthreads();
        sums[t] += v;
        __syncthreads();
    }
    int run = sums[t] - s;  // exclusive prefix
    for (int i = 0; i < 64; ++i) { off[base + i] = run; run += cnt[base + i]; }
    if (t == 1023) off[N_NODES] = run;
}

__global__ void k_fill(const int* __restrict__ srcA, const int* __restrict__ dstA,
                       int* __restrict__ cur, int* __restrict__ csr) {
    int e = blockIdx.x * 256 + threadIdx.x;
    if (e < NE) {
        int p = atomicAdd(&cur[dstA[e]], 1);
        csr[p] = srcA[e];
    }
}

// per-32-node-block degree sort (stable descending) via parallel rank computation.
__global__ void k_bsort(const int* __restrict__ off, int* __restrict__ bperm) {
    __shared__ int degs[256];
    int n = blockIdx.x * 256 + threadIdx.x;
    int deg = off[n + 1] - off[n];
    degs[threadIdx.x] = deg;
    __syncthreads();
    int base32 = threadIdx.x & ~31;
    int i = threadIdx.x & 31;
    int rank = 0;
#pragma unroll
    for (int j = 0; j < 32; ++j) {
        int dj = degs[base32 + j];
        rank += (dj > deg) || (dj == deg && j < i);
    }
    bperm[(n & ~31) + rank] = i;
}

// ---------------- weight packing (MFMA fragment order) ----------------
__global__ void k_cvpack(const float* __restrict__ w, __hip_bfloat16* __restrict__ d) {
    int idx = blockIdx.x * 256 + threadIdx.x;
    if (idx >= 589824) return;
    int j = idx & 7, lane = (idx >> 3) & 63, r = idx >> 9;
    int kk = r & 1; r >>= 1;
    int nt = r & 3; r >>= 2;
    int tap = r % 9, cv = r / 9;
    int co = nt * 16 + (lane & 15);
    int ci = kk * 32 + (lane >> 4) * 8 + j;
    d[idx] = __float2bfloat16(w[((cv * 64 + co) * 64 + ci) * 9 + tap]);
}

__global__ void k_mmpack(const float* __restrict__ Wl, const float* __restrict__ Wr,
                         __hip_bfloat16* __restrict__ d) {
    int idx = blockIdx.x * 256 + threadIdx.x;
    if (idx >= 221184) return;
    int j = idx & 7, lane = (idx >> 3) & 63, r = idx >> 9;
    int kk = r & 1; r >>= 1;
    int nt = r & 3; r >>= 2;
    int side = r & 1, lay = r >> 1;
    int co = nt * 16 + (lane & 15);
    int ci = kk * 32 + (lane >> 4) * 8 + j;
    const float* W = side ? Wr : Wl;
    d[idx] = __float2bfloat16(W[lay * 4096 + ci * 64 + co]);
}

__global__ void k_ccpack(const float* __restrict__ w, __hip_bfloat16* __restrict__ d) {
    int idx = blockIdx.x * 256 + threadIdx.x;
    if (idx >= 36864) return;
    int j = idx & 7;
    int u = idx >> 3;
    int lane = u & 63;
    int f = (u >> 6) & 7;
    int sb = u >> 9;
    int kk = f & 1, nt = f >> 1;
    int br = sb % 3, st = sb / 3;
    int k = br * 64 + kk * 32 + (lane >> 4) * 8 + j;
    int co = nt * 16 + (lane & 15);
    d[idx] = __float2bfloat16(w[st * 12288 + co * 192 + k]);
}

// ---------------- initial NCHW -> [N,64] fp32 + bf16 ----------------
__global__ void k_init(const float* __restrict__ img, float* __restrict__ xn,
                       __hip_bfloat16* __restrict__ xb) {
    __shared__ float tile[64][65];
    int nb = blockIdx.x * 64;
    for (int idx = threadIdx.x; idx < 4096; idx += 256) {
        int c = idx >> 6, n = idx & 63;
        tile[c][n] = img[c * HW + nb + n];
    }
    __syncthreads();
    for (int idx = threadIdx.x; idx < 4096; idx += 256) {
        int n = idx >> 6, c = idx & 63;
        float v = tile[c][n];
        xn[(nb + n) * 64 + c] = v;
        xb[(nb + n) * 64 + c] = __float2bfloat16(v);
    }
}

// ======== mm phase, 32-row tile, 128-thread block (2 waves: one per side) ========
static __device__ __forceinline__ void mm_phase32(char* smem, int t,
        const __hip_bfloat16* __restrict__ pwm, unsigned char* __restrict__ xlo,
        __hip_bfloat16* __restrict__ xrb, int n0) {
    i32x4* la = (i32x4*)smem;
    int lane = t & 63, side = t >> 6;     // wave 0 = XL side, wave 1 = XR side
    const i32x4* wpt = (const i32x4*)pwm + side * 512 + lane;
    f32x4 acc[2][4];
#pragma unroll
    for (int mi = 0; mi < 2; ++mi)
#pragma unroll
        for (int nt = 0; nt < 4; ++nt) acc[mi][nt] = (f32x4)0.0f;
    bf16x8 b[4][2];
#pragma unroll
    for (int nt = 0; nt < 4; ++nt)
#pragma unroll
        for (int kk = 0; kk < 2; ++kk)
            b[nt][kk] = __builtin_bit_cast(bf16x8, wpt[(nt * 2 + kk) * 64]);
#pragma unroll
    for (int mi = 0; mi < 2; ++mi) {
        int row = mi * 16 + (lane & 15);
#pragma unroll
        for (int kk = 0; kk < 2; ++kk) {
            bf16x8 a = __builtin_bit_cast(bf16x8,
                la[row * 8 + (((kk << 2) | (lane >> 4)) ^ (row & 7))]);
#pragma unroll
            for (int nt = 0; nt < 4; ++nt)
                acc[mi][nt] = mfma16(a, b[nt][kk], acc[mi][nt]);
        }
    }
    __syncthreads();                      // la consumed; repurpose as bf16 stage
    unsigned short* ls = (unsigned short*)smem;
    if (side == 0) {
#pragma unroll
        for (int mi = 0; mi < 2; ++mi)
#pragma unroll
            for (int nt = 0; nt < 4; ++nt) {
                int co = nt * 16 + (lane & 15);
#pragma unroll
                for (int r = 0; r < 4; ++r) {
                    int row = mi * 16 + (lane >> 4) * 4 + r;
                    ls[row * 68 + co] = f2bs(acc[mi][nt][r]);
                }
            }
    } else {
#pragma unroll
        for (int mi = 0; mi < 2; ++mi)
#pragma unroll
            for (int nt = 0; nt < 4; ++nt) {
                int co = nt * 16 + (lane & 15);
#pragma unroll
                for (int r = 0; r < 4; ++r) {
                    int node = n0 + mi * 16 + (lane >> 4) * 4 + r;
                    xrb[(size_t)node * 64 + co] = __float2bfloat16(acc[mi][nt][r]);
                }
            }
    }
    __syncthreads();
    for (int u = t; u < 256; u += 128) {      // 32 nodes x 8 channel-octs
        int node = u >> 3, oct = u & 7;
        const unsigned short* p = ls + node * 68 + oct * 8;
        uint2v w0 = *(const uint2v*)p;
        uint2v w1 = *(const uint2v*)(p + 4);
        float f0 = __builtin_bit_cast(float, w0[0] << 16);
        float f1 = __builtin_bit_cast(float, w0[0] & 0xffff0000u);
        float f2 = __builtin_bit_cast(float, w0[1] << 16);
        float f3 = __builtin_bit_cast(float, w0[1] & 0xffff0000u);
        float f4 = __builtin_bit_cast(float, w1[0] << 16);
        float f5 = __builtin_bit_cast(float, w1[0] & 0xffff0000u);
        float f6 = __builtin_bit_cast(float, w1[1] << 16);
        float f7 = __builtin_bit_cast(float, w1[1] & 0xffff0000u);
        int v0 = 0, v1 = 0;
        v0 = __builtin_amdgcn_cvt_pk_fp8_f32(f0, f1, v0, false);
        v0 = __builtin_amdgcn_cvt_pk_fp8_f32(f2, f3, v0, true);
        v1 = __builtin_amdgcn_cvt_pk_fp8_f32(f4, f5, v1, false);
        v1 = __builtin_amdgcn_cvt_pk_fp8_f32(f6, f7, v1, true);
        uint2v o;
        o[0] = (unsigned)v0;
        o[1] = (unsigned)v1;
        *(uint2v*)(xlo + (size_t)(n0 + node) * 64 + oct * 8) = o;
    }
}

// gat node processing (verified math): ELU'd 4-channel result as packed bf16 pair.
static __device__ __forceinline__ uint2v gat_node(
        const unsigned char* __restrict__ xl8, const __hip_bfloat16* __restrict__ xrb,
        const int* __restrict__ csr, const int* __restrict__ csr_c, int cbase, int cc,
        int n, int e0, int e1, int c4, f32x2 a01, f32x2 a23, f32x4 b4) {
    uint2v xw = *(const uint2v*)(xrb + (size_t)n * 64 + c4);
    f32x2 xi01, xi23;
    xi01[0] = __builtin_bit_cast(float, xw[0] << 16);
    xi01[1] = __builtin_bit_cast(float, xw[0] & 0xffff0000u);
    xi23[0] = __builtin_bit_cast(float, xw[1] << 16);
    xi23[1] = __builtin_bit_cast(float, xw[1] & 0xffff0000u);
    float s = 0.f;
    f32x2 acc01 = {0.f, 0.f}, acc23 = {0.f, 0.f};
    int rounds = (e1 - e0 + 1) >> 1;
    int e = e0;
    for (int i = 0; i < rounds; ++i, e += 2) {
        bool aB = (e + 1) < e1;
        int eB = aB ? e + 1 : e;
        int rA = e - cbase, rB = eB - cbase;
        int sA = (rA < cc) ? csr_c[rA] : csr[e];
        int sB = (rB < cc) ? csr_c[rB] : csr[eB];
        unsigned int wA = *(const unsigned int*)(xl8 + (size_t)sA * 64 + c4);
        unsigned int wB = *(const unsigned int*)(xl8 + (size_t)sB * 64 + c4);
        f32x2 xjA01 = __builtin_amdgcn_cvt_pk_f32_fp8((int)wA, false);
        f32x2 xjA23 = __builtin_amdgcn_cvt_pk_f32_fp8((int)wA, true);
        f32x2 xjB01 = __builtin_amdgcn_cvt_pk_f32_fp8((int)wB, false);
        f32x2 xjB23 = __builtin_amdgcn_cvt_pk_f32_fp8((int)wB, true);
        f32x2 vA01 = xi01 + xjA01;
        f32x2 vA23 = xi23 + xjA23;
        vA01 = __builtin_elementwise_max(vA01, vA01 * 0.2f);
        vA23 = __builtin_elementwise_max(vA23, vA23 * 0.2f);
        f32x2 pA2 = vA01 * a01 + vA23 * a23;
        float pA = pA2[0] + pA2[1];
        f32x2 vB01 = xi01 + xjB01;
        f32x2 vB23 = xi23 + xjB23;
        vB01 = __builtin_elementwise_max(vB01, vB01 * 0.2f);
        vB23 = __builtin_elementwise_max(vB23, vB23 * 0.2f);
        f32x2 pB2 = vB01 * a01 + vB23 * a23;
        float pB = pB2[0] + pB2[1];
        pA += __shfl_xor(pA, 1);
        pA += __shfl_xor(pA, 2);
        pB += __shfl_xor(pB, 1);
        pB += __shfl_xor(pB, 2);
        float exA = exp2f(fmaxf(pA, -100.f));
        float exB = exp2f(fmaxf(pB, -100.f));
        exB = aB ? exB : 0.f;
        s += exA + exB;
        acc01 = acc01 + exA * xjA01 + exB * xjB01;
        acc23 = acc23 + exA * xjA23 + exB * xjB23;
    }
    float inv = __builtin_amdgcn_rcpf(s + 1e-16f);
    float v0 = fmaf(acc01[0], inv, b4[0]);
    float v1 = fmaf(acc01[1], inv, b4[1]);
    float v2 = fmaf(acc23[0], inv, b4[2]);
    float v3 = fmaf(acc23[1], inv, b4[3]);
    v0 = v0 > 0.f ? v0 : __expf(v0) - 1.f;
    v1 = v1 > 0.f ? v1 : __expf(v1) - 1.f;
    v2 = v2 > 0.f ? v2 : __expf(v2) - 1.f;
    v3 = v3 > 0.f ? v3 : __expf(v3) - 1.f;
    uint2v o;
    o[0] = (unsigned)f2bs(v0) | ((unsigned)f2bs(v1) << 16);
    o[1] = (unsigned)f2bs(v2) | ((unsigned)f2bs(v3) << 16);
    return o;
}

// ---------------- k_mm3: layer-0 dual matmul, 3 modules, 32-node blocks ----------------
__global__ __launch_bounds__(128) void k_mm3(const __hip_bfloat16* __restrict__ Xb,
        const __hip_bfloat16* __restrict__ pw, unsigned char* __restrict__ XL8,
        __hip_bfloat16* __restrict__ XRb) {
    __shared__ i32x4 smem4[272];          // 4352 B union
    char* smem = (char*)smem4;
    i32x4* la = (i32x4*)smem;
    int t = threadIdx.x;
    int m = blockIdx.x >> 11;
    int n0 = (blockIdx.x & 2047) << 5;
    const i32x4* Xg = (const i32x4*)Xb + n0 * 8;
    for (int idx = t; idx < 256; idx += 128) {
        int r = idx >> 3, c = idx & 7;
        la[r * 8 + (c ^ (r & 7))] = Xg[idx];
    }
    __syncthreads();
    mm_phase32(smem, t, pw + m * 24576, XL8 + (size_t)m * NC,
               XRb + (size_t)m * NC, n0);
}

// ---------------- k_fuse: GAT(l) for 32 nodes -> LDS -> MM(l+1) ----------------
__global__ __launch_bounds__(128) void k_fuse(
        const unsigned char* __restrict__ XL8in, unsigned char* __restrict__ XL8out,
        __hip_bfloat16* __restrict__ XRb, const float* __restrict__ gatt,
        const float* __restrict__ gb, const __hip_bfloat16* __restrict__ pw,
        const int* __restrict__ off, const int* __restrict__ csr,
        const int* __restrict__ bperm) {
    __shared__ i32x4 smem4[272];          // 4352 B union
    __shared__ int csr_c[384];
    char* smem = (char*)smem4;
    int t = threadIdx.x;
    int p = blockIdx.x;
    int vi = (p & 7) * 768 + (p >> 3);    // xcd-contiguous remap (6144 blocks)
    int m = vi >> 11;
    int n0 = (vi & 2047) << 5;
    const unsigned char* xl8 = XL8in + (size_t)m * NC;
    unsigned char* xlo = XL8out + (size_t)m * NC;
    __hip_bfloat16* xrb = XRb + (size_t)m * NC;
    int cbase = off[n0];
    int cc = min(off[n0 + 32] - cbase, 384);
    for (int i = t; i < cc; i += 128) csr_c[i] = csr[cbase + i];
    __syncthreads();
    int g16 = t >> 4;                      // group 0..7, 4 nodes each
    int c4 = (t & 15) << 2;
    const float* at = gatt + m * 192;
    const float* bb = gb + m * 192;
    const float LOG2E = 1.44269504089f;
    f32x4 a4 = *(const f32x4*)(at + c4);
    f32x2 a01 = {a4[0] * LOG2E, a4[1] * LOG2E};
    f32x2 a23 = {a4[2] * LOG2E, a4[3] * LOG2E};
    f32x4 b4 = *(const f32x4*)(bb + c4);
    uint2v* lau = (uint2v*)smem;
    int cchunk = c4 >> 3, half = (c4 >> 2) & 1;
    const int* bp = bperm + n0;
#pragma unroll
    for (int nn = 0; nn < 4; ++nn) {
        int rank = (nn & 1) ? (nn * 8 + (7 - g16)) : (nn * 8 + g16);  // snake
        int r = bp[rank];
        int n = n0 + r;
        uint2v o = gat_node(xl8, xrb, csr, csr_c, cbase, cc, n,
                            off[n], off[n + 1], c4, a01, a23, b4);
        lau[(r * 8 + (cchunk ^ (r & 7))) * 2 + half] = o;
    }
    __syncthreads();
    mm_phase32(smem, t, pw + m * 24576, xlo, xrb, n0);
}

// ---------------- k_gatcc: final GAT layer (3 modules interleaved) + 1x1 conv ----------
// block = 16 nodes (ranks of half a 32-node sorted window), 256 threads.
// Group g (16 lanes) = one node, all 3 modules in one edge loop (6 gathers in
// flight, identical degree -> zero waste, csr/index math shared). Results to
// LDS [16][192] swizzled A-tile -> K=192 MFMA -> bias + residual -> out.
template <int FINAL>
__global__ __launch_bounds__(256) void k_gatcc(
        const unsigned char* __restrict__ XL8, const __hip_bfloat16* __restrict__ XRb,
        const float* __restrict__ gatt, const float* __restrict__ gb,
        const __hip_bfloat16* __restrict__ ccw, const float* __restrict__ ccbias,
        const int* __restrict__ off, const int* __restrict__ csr,
        const int* __restrict__ bperm, const float* __restrict__ resin,
        float* __restrict__ imgout, __hip_bfloat16* __restrict__ outb,
        float* __restrict__ outp) {
    __shared__ int csr_c[384];
    __shared__ int nid[16];
    __shared__ i32x4 la[16 * 24];         // [16 rows][192 ch] bf16, swizzled
    int t = threadIdx.x;
    int p = blockIdx.x;
    int vi = (p & 7) * 512 + (p >> 3);    // xcd-contiguous remap (4096 blocks)
    int base32 = (vi >> 1) << 5;
    int half16 = vi & 1;
    int cbase = off[base32];
    int cc = min(off[base32 + 32] - cbase, 384);
    for (int i = t; i < cc; i += 256) csr_c[i] = csr[cbase + i];
    if (t < 16) nid[t] = base32 + bperm[base32 + half16 * 16 + t];
    __syncthreads();
    int g = t >> 4;                        // group = row 0..15
    int c4 = (t & 15) << 2;
    int n = nid[g];
    int e0 = off[n], e1 = off[n + 1];
    const float LOG2E = 1.44269504089f;
    f32x2 a01[3], a23[3];
    f32x4 b4[3];
    f32x2 xi01[3], xi23[3];
    float s[3];
    f32x2 ac01[3], ac23[3];
#pragma unroll
    for (int m = 0; m < 3; ++m) {
        f32x4 a4 = *(const f32x4*)(gatt + m * 192 + c4);
        a01[m][0] = a4[0] * LOG2E; a01[m][1] = a4[1] * LOG2E;
        a23[m][0] = a4[2] * LOG2E; a23[m][1] = a4[3] * LOG2E;
        b4[m] = *(const f32x4*)(gb + m * 192 + c4);
        uint2v xw = *(const uint2v*)(XRb + (size_t)m * NC + (size_t)n * 64 + c4);
        xi01[m][0] = __builtin_bit_cast(float, xw[0] << 16);
        xi01[m][1] = __builtin_bit_cast(float, xw[0] & 0xffff0000u);
        xi23[m][0] = __builtin_bit_cast(float, xw[1] << 16);
        xi23[m][1] = __builtin_bit_cast(float, xw[1] & 0xffff0000u);
        s[m] = 0.f;
        ac01[m][0] = 0.f; ac01[m][1] = 0.f;
        ac23[m][0] = 0.f; ac23[m][1] = 0.f;
    }
    int rounds = (e1 - e0 + 1) >> 1;
    int e = e0;
    for (int i = 0; i < rounds; ++i, e += 2) {
        bool aB = (e + 1) < e1;
        int eB = aB ? e + 1 : e;
        int rA = e - cbase, rB = eB - cbase;
        int sA = (rA < cc) ? csr_c[rA] : csr[e];
        int sB = (rB < cc) ? csr_c[rB] : csr[eB];
        size_t oA = (size_t)sA * 64 + c4, oB = (size_t)sB * 64 + c4;
#pragma unroll
        for (int m = 0; m < 3; ++m) {
            unsigned int wA = *(const unsigned int*)(XL8 + (size_t)m * NC + oA);
            unsigned int wB = *(const unsigned int*)(XL8 + (size_t)m * NC + oB);
            f32x2 xjA01 = __builtin_amdgcn_cvt_pk_f32_fp8((int)wA, false);
            f32x2 xjA23 = __builtin_amdgcn_cvt_pk_f32_fp8((int)wA, true);
            f32x2 xjB01 = __builtin_amdgcn_cvt_pk_f32_fp8((int)wB, false);
            f32x2 xjB23 = __builtin_amdgcn_cvt_pk_f32_fp8((int)wB, true);
            f32x2 vA01 = xi01[m] + xjA01;
            f32x2 vA23 = xi23[m] + xjA23;
            vA01 = __builtin_elementwise_max(vA01, vA01 * 0.2f);
            vA23 = __builtin_elementwise_max(vA23, vA23 * 0.2f);
            f32x2 pA2 = vA01 * a01[m] + vA23 * a23[m];
            float pA = pA2[0] + pA2[1];
            f32x2 vB01 = xi01[m] + xjB01;
            f32x2 vB23 = xi23[m] + xjB23;
            vB01 = __builtin_elementwise_max(vB01, vB01 * 0.2f);
            vB23 = __builtin_elementwise_max(vB23, vB23 * 0.2f);
            f32x2 pB2 = vB01 * a01[m] + vB23 * a23[m];
            float pB = pB2[0] + pB2[1];
            pA += __shfl_xor(pA, 1);
            pA += __shfl_xor(pA, 2);
            pB += __shfl_xor(pB, 1);
            pB += __shfl_xor(pB, 2);
            float exA = exp2f(fmaxf(pA, -100.f));
            float exB = exp2f(fmaxf(pB, -100.f));
            exB = aB ? exB : 0.f;
            s[m] += exA + exB;
            ac01[m] = ac01[m] + exA * xjA01 + exB * xjB01;
            ac23[m] = ac23[m] + exA * xjA23 + exB * xjB23;
        }
    }
    uint2v* lau = (uint2v*)la;
#pragma unroll
    for (int m = 0; m < 3; ++m) {
        float inv = __builtin_amdgcn_rcpf(s[m] + 1e-16f);
        float v0 = fmaf(ac01[m][0], inv, b4[m][0]);
        float v1 = fmaf(ac01[m][1], inv, b4[m][1]);
        float v2 = fmaf(ac23[m][0], inv, b4[m][2]);
        float v3 = fmaf(ac23[m][1], inv, b4[m][3]);
        v0 = v0 > 0.f ? v0 : __expf(v0) - 1.f;
        v1 = v1 > 0.f ? v1 : __expf(v1) - 1.f;
        v2 = v2 > 0.f ? v2 : __expf(v2) - 1.f;
        v3 = v3 > 0.f ? v3 : __expf(v3) - 1.f;
        uint2v o;
        o[0] = (unsigned)f2bs(v0) | ((unsigned)f2bs(v1) << 16);
        o[1] = (unsigned)f2bs(v2) | ((unsigned)f2bs(v3) << 16);
        int ch = m * 8 + (c4 >> 3);
        int swz = (ch & 24) | ((ch & 7) ^ (g & 7));
        lau[(g * 24 + swz) * 2 + ((c4 >> 2) & 1)] = o;
    }
    __syncthreads();
    // ---- 1x1 conv: [16 rows] x [64 co], K=192 ----
    int lane = t & 63, w = t >> 6;         // wave w handles co tile nt=w
    f32x4 acc = (f32x4)0.0f;
    const i32x4* wp4 = (const i32x4*)ccw;
#pragma unroll
    for (int kkg = 0; kkg < 6; ++kkg) {
        int br = kkg >> 1, kk2 = kkg & 1;
        bf16x8 bfr = __builtin_bit_cast(bf16x8,
            wp4[(br * 8 + w * 2 + kk2) * 64 + lane]);
        int row = lane & 15;
        int ch = kkg * 4 + (lane >> 4);
        int swz = (ch & 24) | ((ch & 7) ^ (row & 7));
        bf16x8 afr = __builtin_bit_cast(bf16x8, la[row * 24 + swz]);
        acc = mfma16(afr, bfr, acc);
    }
    int co = w * 16 + (lane & 15);
    float bv = ccbias[co];
#pragma unroll
    for (int r = 0; r < 4; ++r) {
        int row = (lane >> 4) * 4 + r;
        int nn = nid[row];
        float v = acc[r] + bv + resin[(size_t)nn * 64 + co];
        if (FINAL) {
            outp[(size_t)co * HW + nn] = v;
        } else {
            imgout[(size_t)nn * 64 + co] = v;
            outb[(size_t)nn * 64 + co] = __float2bfloat16(v);
        }
    }
}

// ---------------- 3x3 conv 64->64, channels-last, MFMA, 64-pixel blocks ----------------
template <int MODE>
__global__ __launch_bounds__(256) void k_conv(const __hip_bfloat16* __restrict__ inb,
        const __hip_bfloat16* __restrict__ wp, const float* __restrict__ bias,
        const float* __restrict__ pa, float* __restrict__ img,
        __hip_bfloat16* __restrict__ outb) {
    __shared__ i32x4 la[2][66 * 8];
    int t = threadIdx.x, lane = t & 63, wid = t >> 6;
    int y = blockIdx.x >> 2, x0 = (blockIdx.x & 3) << 6;
    f32x4 acc[4];
#pragma unroll
    for (int nt = 0; nt < 4; ++nt) acc[nt] = (f32x4)0.0f;
    const i32x4* ing = (const i32x4*)inb;
    auto stage = [&](int dy, int buf) {
        int sy = y + dy - 1;
        bool rowok = (sy >= 0) && (sy < 256);
        for (int idx = t; idx < 528; idx += 256) {
            int r = idx >> 3, c = idx & 7;
            int sx = x0 - 1 + r;
            i32x4 v = (i32x4)0;
            if (rowok && sx >= 0 && sx < 256) v = ing[(sy * 256 + sx) * 8 + c];
            la[buf][r * 8 + (c ^ (r & 7))] = v;
        }
    };
    stage(0, 0);
    __syncthreads();
#pragma unroll
    for (int dy = 0; dy < 3; ++dy) {
        if (dy < 2) stage(dy + 1, (dy + 1) & 1);
        const i32x4* lb = la[dy & 1];
#pragma unroll
        for (int dx = 0; dx < 3; ++dx) {
            const i32x4* wpt = (const i32x4*)wp + (dy * 3 + dx) * 512 + lane;
            bf16x8 b[4][2];
#pragma unroll
            for (int nt = 0; nt < 4; ++nt)
#pragma unroll
                for (int kk = 0; kk < 2; ++kk)
                    b[nt][kk] = __builtin_bit_cast(bf16x8, wpt[(nt * 2 + kk) * 64]);
            int row = dx + wid * 16 + (lane & 15);
#pragma unroll
            for (int kk = 0; kk < 2; ++kk) {
                bf16x8 a = __builtin_bit_cast(bf16x8,
                    lb[row * 8 + (((kk << 2) | (lane >> 4)) ^ (row & 7))]);
#pragma unroll
                for (int nt = 0; nt < 4; ++nt)
                    acc[nt] = mfma16(a, b[nt][kk], acc[nt]);
            }
        }
        __syncthreads();
    }
    int pbase = y * 256 + x0 + wid * 16 + (lane >> 4) * 4;
    float aprelu = (MODE == 0) ? pa[0] : 0.f;
#pragma unroll
    for (int nt = 0; nt < 4; ++nt) {
        int co = nt * 16 + (lane & 15);
        float bv = bias[co];
#pragma unroll
        for (int r = 0; r < 4; ++r) {
            int pix = pbase + r;
            float v = acc[nt][r] + bv;
            if (MODE == 0) {
                v = v >= 0.f ? v : aprelu * v;
                outb[pix * 64 + co] = __float2bfloat16(v);
            } else {
                v += img[pix * 64 + co];
                img[pix * 64 + co] = v;
                outb[pix * 64 + co] = __float2bfloat16(v);
            }
        }
    }
}

// ---------------- host ----------------
extern "C" void kernel_launch(void* const* d_in, const int* in_sizes, int n_in,
                              void* d_out, int out_size, void* d_ws, size_t ws_size,
                              hipStream_t stream) {
    const float* x    = (const float*)d_in[0];
    const int*   ei   = (const int*)d_in[1];
    const float* gWl  = (const float*)d_in[2];   // [27][64][64]
    const float* gWr  = (const float*)d_in[3];
    const float* gatt = (const float*)d_in[4];   // [27][64]
    const float* gb   = (const float*)d_in[5];   // [27][64]
    const float* ccw  = (const float*)d_in[6];   // [3][64][192]
    const float* ccb  = (const float*)d_in[7];   // [3][64]
    const float* rbw  = (const float*)d_in[8];   // [16][64][64][3][3]
    const float* rbb  = (const float*)d_in[9];   // [16][64]
    const float* rba  = (const float*)d_in[10];  // [8]
    float* outp = (float*)d_out;

    float* wsf = (float*)d_ws;
    float* xn  = wsf;                              // NC f32
    float* img = xn + NC;                          // NC f32
    __hip_bfloat16* xrb3 = (__hip_bfloat16*)(img + NC);     // 3*NC bf16
    unsigned char* xl8p0 = (unsigned char*)(xrb3 + 3 * (size_t)NC);  // 3*NC B
    unsigned char* xl8p1 = xl8p0 + 3 * (size_t)NC;                    // 3*NC B
    __hip_bfloat16* xb   = (__hip_bfloat16*)(xl8p1 + 3 * (size_t)NC);
    __hip_bfloat16* cvb  = xb + NC;                // conv temp
    __hip_bfloat16* wpkc = cvb + NC;               // 589824
    __hip_bfloat16* wpkm = wpkc + 589824;          // 221184
    __hip_bfloat16* ccpk = wpkm + 221184;          // 36864
    int* ioff = (int*)(ccpk + 36864);
    int* icnt = ioff + (N_NODES + 1);
    int* icur = icnt + N_NODES;
    int* icsr = icur + N_NODES;                    // NE
    int* ibperm = icsr + NE;                       // N

    const int* srcA = ei;
    const int* dstA = ei + NE;

    hipMemsetAsync(icnt, 0, N_NODES * sizeof(int), stream);
    k_hist<<<NE / 256, 256, 0, stream>>>(dstA, icnt);
    k_scan<<<1, 1024, 0, stream>>>(icnt, ioff);
    hipMemcpyAsync(icur, ioff, N_NODES * sizeof(int), hipMemcpyDeviceToDevice, stream);
    k_fill<<<NE / 256, 256, 0, stream>>>(srcA, dstA, icur, icsr);
    k_bsort<<<N_NODES / 256, 256, 0, stream>>>(ioff, ibperm);
    k_cvpack<<<2304, 256, 0, stream>>>(rbw, wpkc);
    k_mmpack<<<864, 256, 0, stream>>>(gWl, gWr, wpkm);
    k_ccpack<<<144, 256, 0, stream>>>(ccw, ccpk);
    k_init<<<1024, 256, 0, stream>>>(x, xn, xb);

    for (int st = 0; st < 3; ++st) {
        int L = st * 9;
        k_mm3<<<6144, 128, 0, stream>>>(xb, wpkm + (size_t)L * 8192, xl8p0, xrb3);
        k_fuse<<<6144, 128, 0, stream>>>(xl8p0, xl8p1, xrb3,
            gatt + L * 64, gb + L * 64, wpkm + (size_t)(L + 1) * 8192, ioff, icsr,
            ibperm);
        k_fuse<<<6144, 128, 0, stream>>>(xl8p1, xl8p0, xrb3,
            gatt + (L + 1) * 64, gb + (L + 1) * 64, wpkm + (size_t)(L + 2) * 8192,
            ioff, icsr, ibperm);
        const float* resin = (st == 0) ? xn : img;
        if (st == 2) {
            k_gatcc<1><<<4096, 256, 0, stream>>>(xl8p0, xrb3,
                gatt + (L + 2) * 64, gb + (L + 2) * 64, ccpk + 2 * 12288, ccb + 128,
                ioff, icsr, ibperm, resin, nullptr, nullptr, outp);
        } else {
            k_gatcc<0><<<4096, 256, 0, stream>>>(xl8p0, xrb3,
                gatt + (L + 2) * 64, gb + (L + 2) * 64, ccpk + st * 12288,
                ccb + st * 64, ioff, icsr, ibperm, resin, img, xb, nullptr);
            for (int bk = 0; bk < 4; ++bk) {
                int cv = (st * 4 + bk) * 2;
                k_conv<0><<<1024, 256, 0, stream>>>(xb, wpkc + (size_t)cv * 36864,
                    rbb + cv * 64, rba + st * 4 + bk, nullptr, cvb);
                k_conv<1><<<1024, 256, 0, stream>>>(cvb, wpkc + (size_t)(cv + 1) * 36864,
                    rbb + (cv + 1) * 64, nullptr, img, xb);
            }
        }
    }
}

// Round 19
// 901.930 us; speedup vs baseline: 1.0119x; 1.0119x over previous
//
#include <hip/hip_runtime.h>
#include <hip/hip_bf16.h>
#include <math.h>

#define N_NODES 65536
#define HW      65536
#define NE      524288
#define NC      (N_NODES * 64)

typedef __bf16 bf16x8 __attribute__((ext_vector_type(8)));
typedef float  f32x4  __attribute__((ext_vector_type(4)));
typedef float  f32x2  __attribute__((ext_vector_type(2)));
typedef int    i32x4  __attribute__((ext_vector_type(4)));
typedef unsigned int uint2v __attribute__((ext_vector_type(2)));

static __device__ __forceinline__ f32x4 mfma16(bf16x8 a, bf16x8 b, f32x4 c) {
    return __builtin_amdgcn_mfma_f32_16x16x32_bf16(a, b, c, 0, 0, 0);
}

static __device__ __forceinline__ unsigned short f2bs(float f) {
    return __builtin_bit_cast(unsigned short, __float2bfloat16(f));
}

// ---------------- CSR build ----------------
__global__ void k_hist(const int* __restrict__ dstA, int* __restrict__ cnt) {
    int e = blockIdx.x * 256 + threadIdx.x;
    if (e < NE) atomicAdd(&cnt[dstA[e]], 1);
}

__global__ void k_scan(const int* __restrict__ cnt, int* __restrict__ off) {
    __shared__ int sums[1024];
    int t = threadIdx.x;
    int base = t * 64;
    int s = 0;
    for (int i = 0; i < 64; ++i) s += cnt[base + i];
    sums[t] = s;
    __syncthreads();
    for (int d = 1; d < 1024; d <<= 1) {
        int v = (t >= d) ? sums[t - d] : 0;
        __syncthreads();
        sums[t] += v;
        __syncthreads();
    }
    int run = sums[t] - s;  // exclusive prefix
    for (int i = 0; i < 64; ++i) { off[base + i] = run; run += cnt[base + i]; }
    if (t == 1023) off[N_NODES] = run;
}

__global__ void k_fill(const int* __restrict__ srcA, const int* __restrict__ dstA,
                       int* __restrict__ cur, int* __restrict__ csr) {
    int e = blockIdx.x * 256 + threadIdx.x;
    if (e < NE) {
        int p = atomicAdd(&cur[dstA[e]], 1);
        csr[p] = srcA[e];
    }
}

// per-32-node-block degree sort (stable descending) via parallel rank computation.
// One thread per node; all-static indexing (no scratch). Bitwise-identical to a
// stable insertion sort. Processing-order only -> results unchanged.
__global__ void k_bsort(const int* __restrict__ off, int* __restrict__ bperm) {
    __shared__ int degs[256];
    int n = blockIdx.x * 256 + threadIdx.x;
    int deg = off[n + 1] - off[n];
    degs[threadIdx.x] = deg;
    __syncthreads();
    int base32 = threadIdx.x & ~31;
    int i = threadIdx.x & 31;
    int rank = 0;
#pragma unroll
    for (int j = 0; j < 32; ++j) {
        int dj = degs[base32 + j];
        rank += (dj > deg) || (dj == deg && j < i);
    }
    bperm[(n & ~31) + rank] = i;
}

// ---------------- weight packing (MFMA fragment order) ----------------
__global__ void k_cvpack(const float* __restrict__ w, __hip_bfloat16* __restrict__ d) {
    int idx = blockIdx.x * 256 + threadIdx.x;
    if (idx >= 589824) return;
    int j = idx & 7, lane = (idx >> 3) & 63, r = idx >> 9;
    int kk = r & 1; r >>= 1;
    int nt = r & 3; r >>= 2;
    int tap = r % 9, cv = r / 9;
    int co = nt * 16 + (lane & 15);
    int ci = kk * 32 + (lane >> 4) * 8 + j;
    d[idx] = __float2bfloat16(w[((cv * 64 + co) * 64 + ci) * 9 + tap]);
}

__global__ void k_mmpack(const float* __restrict__ Wl, const float* __restrict__ Wr,
                         __hip_bfloat16* __restrict__ d) {
    int idx = blockIdx.x * 256 + threadIdx.x;
    if (idx >= 221184) return;
    int j = idx & 7, lane = (idx >> 3) & 63, r = idx >> 9;
    int kk = r & 1; r >>= 1;
    int nt = r & 3; r >>= 2;
    int side = r & 1, lay = r >> 1;
    int co = nt * 16 + (lane & 15);
    int ci = kk * 32 + (lane >> 4) * 8 + j;
    const float* W = side ? Wr : Wl;
    d[idx] = __float2bfloat16(W[lay * 4096 + ci * 64 + co]);
}

__global__ void k_ccpack(const float* __restrict__ w, __hip_bfloat16* __restrict__ d) {
    int idx = blockIdx.x * 256 + threadIdx.x;
    if (idx >= 36864) return;
    int j = idx & 7;
    int u = idx >> 3;
    int lane = u & 63;
    int f = (u >> 6) & 7;
    int sb = u >> 9;
    int kk = f & 1, nt = f >> 1;
    int br = sb % 3, st = sb / 3;
    int k = br * 64 + kk * 32 + (lane >> 4) * 8 + j;
    int co = nt * 16 + (lane & 15);
    d[idx] = __float2bfloat16(w[st * 12288 + co * 192 + k]);
}

// ---------------- initial NCHW -> [N,64] fp32 + bf16 ----------------
__global__ void k_init(const float* __restrict__ img, float* __restrict__ xn,
                       __hip_bfloat16* __restrict__ xb) {
    __shared__ float tile[64][65];
    int nb = blockIdx.x * 64;
    for (int idx = threadIdx.x; idx < 4096; idx += 256) {
        int c = idx >> 6, n = idx & 63;
        tile[c][n] = img[c * HW + nb + n];
    }
    __syncthreads();
    for (int idx = threadIdx.x; idx < 4096; idx += 256) {
        int n = idx >> 6, c = idx & 63;
        float v = tile[c][n];
        xn[(nb + n) * 64 + c] = v;
        xb[(nb + n) * 64 + c] = __float2bfloat16(v);
    }
}

// ======== mm phase, 32-row tile, 128-thread block (2 waves: one per side) ========
static __device__ __forceinline__ void mm_phase32(char* smem, int t,
        const __hip_bfloat16* __restrict__ pwm, unsigned char* __restrict__ xlo,
        __hip_bfloat16* __restrict__ xrb, int n0) {
    i32x4* la = (i32x4*)smem;
    int lane = t & 63, side = t >> 6;     // wave 0 = XL side, wave 1 = XR side
    const i32x4* wpt = (const i32x4*)pwm + side * 512 + lane;
    f32x4 acc[2][4];
#pragma unroll
    for (int mi = 0; mi < 2; ++mi)
#pragma unroll
        for (int nt = 0; nt < 4; ++nt) acc[mi][nt] = (f32x4)0.0f;
    bf16x8 b[4][2];
#pragma unroll
    for (int nt = 0; nt < 4; ++nt)
#pragma unroll
        for (int kk = 0; kk < 2; ++kk)
            b[nt][kk] = __builtin_bit_cast(bf16x8, wpt[(nt * 2 + kk) * 64]);
#pragma unroll
    for (int mi = 0; mi < 2; ++mi) {
        int row = mi * 16 + (lane & 15);
#pragma unroll
        for (int kk = 0; kk < 2; ++kk) {
            bf16x8 a = __builtin_bit_cast(bf16x8,
                la[row * 8 + (((kk << 2) | (lane >> 4)) ^ (row & 7))]);
#pragma unroll
            for (int nt = 0; nt < 4; ++nt)
                acc[mi][nt] = mfma16(a, b[nt][kk], acc[mi][nt]);
        }
    }
    __syncthreads();                      // la consumed; repurpose as bf16 stage
    unsigned short* ls = (unsigned short*)smem;
    if (side == 0) {
#pragma unroll
        for (int mi = 0; mi < 2; ++mi)
#pragma unroll
            for (int nt = 0; nt < 4; ++nt) {
                int co = nt * 16 + (lane & 15);
#pragma unroll
                for (int r = 0; r < 4; ++r) {
                    int row = mi * 16 + (lane >> 4) * 4 + r;
                    ls[row * 68 + co] = f2bs(acc[mi][nt][r]);
                }
            }
    } else {
#pragma unroll
        for (int mi = 0; mi < 2; ++mi)
#pragma unroll
            for (int nt = 0; nt < 4; ++nt) {
                int co = nt * 16 + (lane & 15);
#pragma unroll
                for (int r = 0; r < 4; ++r) {
                    int node = n0 + mi * 16 + (lane >> 4) * 4 + r;
                    xrb[(size_t)node * 64 + co] = __float2bfloat16(acc[mi][nt][r]);
                }
            }
    }
    __syncthreads();
    for (int u = t; u < 256; u += 128) {      // 32 nodes x 8 channel-octs
        int node = u >> 3, oct = u & 7;
        const unsigned short* p = ls + node * 68 + oct * 8;
        uint2v w0 = *(const uint2v*)p;
        uint2v w1 = *(const uint2v*)(p + 4);
        float f0 = __builtin_bit_cast(float, w0[0] << 16);
        float f1 = __builtin_bit_cast(float, w0[0] & 0xffff0000u);
        float f2 = __builtin_bit_cast(float, w0[1] << 16);
        float f3 = __builtin_bit_cast(float, w0[1] & 0xffff0000u);
        float f4 = __builtin_bit_cast(float, w1[0] << 16);
        float f5 = __builtin_bit_cast(float, w1[0] & 0xffff0000u);
        float f6 = __builtin_bit_cast(float, w1[1] << 16);
        float f7 = __builtin_bit_cast(float, w1[1] & 0xffff0000u);
        int v0 = 0, v1 = 0;
        v0 = __builtin_amdgcn_cvt_pk_fp8_f32(f0, f1, v0, false);
        v0 = __builtin_amdgcn_cvt_pk_fp8_f32(f2, f3, v0, true);
        v1 = __builtin_amdgcn_cvt_pk_fp8_f32(f4, f5, v1, false);
        v1 = __builtin_amdgcn_cvt_pk_fp8_f32(f6, f7, v1, true);
        uint2v o;
        o[0] = (unsigned)v0;
        o[1] = (unsigned)v1;
        *(uint2v*)(xlo + (size_t)(n0 + node) * 64 + oct * 8) = o;
    }
}

// gat node processing (verified math): ELU'd 4-channel result as packed bf16 pair.
static __device__ __forceinline__ uint2v gat_node(
        const unsigned char* __restrict__ xl8, const __hip_bfloat16* __restrict__ xrb,
        const int* __restrict__ csr, const int* __restrict__ csr_c, int cbase, int cc,
        int n, int e0, int e1, int c4, f32x2 a01, f32x2 a23, f32x4 b4) {
    uint2v xw = *(const uint2v*)(xrb + (size_t)n * 64 + c4);
    f32x2 xi01, xi23;
    xi01[0] = __builtin_bit_cast(float, xw[0] << 16);
    xi01[1] = __builtin_bit_cast(float, xw[0] & 0xffff0000u);
    xi23[0] = __builtin_bit_cast(float, xw[1] << 16);
    xi23[1] = __builtin_bit_cast(float, xw[1] & 0xffff0000u);
    float s = 0.f;
    f32x2 acc01 = {0.f, 0.f}, acc23 = {0.f, 0.f};
    int rounds = (e1 - e0 + 1) >> 1;
    int e = e0;
    for (int i = 0; i < rounds; ++i, e += 2) {
        bool aB = (e + 1) < e1;
        int eB = aB ? e + 1 : e;
        int rA = e - cbase, rB = eB - cbase;
        int sA = (rA < cc) ? csr_c[rA] : csr[e];
        int sB = (rB < cc) ? csr_c[rB] : csr[eB];
        unsigned int wA = *(const unsigned int*)(xl8 + (size_t)sA * 64 + c4);
        unsigned int wB = *(const unsigned int*)(xl8 + (size_t)sB * 64 + c4);
        f32x2 xjA01 = __builtin_amdgcn_cvt_pk_f32_fp8((int)wA, false);
        f32x2 xjA23 = __builtin_amdgcn_cvt_pk_f32_fp8((int)wA, true);
        f32x2 xjB01 = __builtin_amdgcn_cvt_pk_f32_fp8((int)wB, false);
        f32x2 xjB23 = __builtin_amdgcn_cvt_pk_f32_fp8((int)wB, true);
        f32x2 vA01 = xi01 + xjA01;
        f32x2 vA23 = xi23 + xjA23;
        vA01 = __builtin_elementwise_max(vA01, vA01 * 0.2f);
        vA23 = __builtin_elementwise_max(vA23, vA23 * 0.2f);
        f32x2 pA2 = vA01 * a01 + vA23 * a23;
        float pA = pA2[0] + pA2[1];
        f32x2 vB01 = xi01 + xjB01;
        f32x2 vB23 = xi23 + xjB23;
        vB01 = __builtin_elementwise_max(vB01, vB01 * 0.2f);
        vB23 = __builtin_elementwise_max(vB23, vB23 * 0.2f);
        f32x2 pB2 = vB01 * a01 + vB23 * a23;
        float pB = pB2[0] + pB2[1];
        pA += __shfl_xor(pA, 1);
        pA += __shfl_xor(pA, 2);
        pB += __shfl_xor(pB, 1);
        pB += __shfl_xor(pB, 2);
        float exA = exp2f(fmaxf(pA, -100.f));
        float exB = exp2f(fmaxf(pB, -100.f));
        exB = aB ? exB : 0.f;
        s += exA + exB;
        acc01 = acc01 + exA * xjA01 + exB * xjB01;
        acc23 = acc23 + exA * xjA23 + exB * xjB23;
    }
    float inv = __builtin_amdgcn_rcpf(s + 1e-16f);
    float v0 = fmaf(acc01[0], inv, b4[0]);
    float v1 = fmaf(acc01[1], inv, b4[1]);
    float v2 = fmaf(acc23[0], inv, b4[2]);
    float v3 = fmaf(acc23[1], inv, b4[3]);
    v0 = v0 > 0.f ? v0 : __expf(v0) - 1.f;
    v1 = v1 > 0.f ? v1 : __expf(v1) - 1.f;
    v2 = v2 > 0.f ? v2 : __expf(v2) - 1.f;
    v3 = v3 > 0.f ? v3 : __expf(v3) - 1.f;
    uint2v o;
    o[0] = (unsigned)f2bs(v0) | ((unsigned)f2bs(v1) << 16);
    o[1] = (unsigned)f2bs(v2) | ((unsigned)f2bs(v3) << 16);
    return o;
}

// ---------------- k_mm3: layer-0 dual matmul, 3 modules, 32-node blocks ----------------
__global__ __launch_bounds__(128) void k_mm3(const __hip_bfloat16* __restrict__ Xb,
        const __hip_bfloat16* __restrict__ pw, unsigned char* __restrict__ XL8,
        __hip_bfloat16* __restrict__ XRb) {
    __shared__ i32x4 smem4[272];          // 4352 B union
    char* smem = (char*)smem4;
    i32x4* la = (i32x4*)smem;
    int t = threadIdx.x;
    int m = blockIdx.x >> 11;
    int n0 = (blockIdx.x & 2047) << 5;
    const i32x4* Xg = (const i32x4*)Xb + n0 * 8;
    for (int idx = t; idx < 256; idx += 128) {
        int r = idx >> 3, c = idx & 7;
        la[r * 8 + (c ^ (r & 7))] = Xg[idx];
    }
    __syncthreads();
    mm_phase32(smem, t, pw + m * 24576, XL8 + (size_t)m * NC,
               XRb + (size_t)m * NC, n0);
}

// ---------------- k_fuse: GAT(l) for 32 nodes -> LDS -> MM(l+1) ----------------
// snake-balanced node assignment via per-block degree sort (bperm).
__global__ __launch_bounds__(128) void k_fuse(
        const unsigned char* __restrict__ XL8in, unsigned char* __restrict__ XL8out,
        __hip_bfloat16* __restrict__ XRb, const float* __restrict__ gatt,
        const float* __restrict__ gb, const __hip_bfloat16* __restrict__ pw,
        const int* __restrict__ off, const int* __restrict__ csr,
        const int* __restrict__ bperm) {
    __shared__ i32x4 smem4[272];          // 4352 B union
    __shared__ int csr_c[384];
    char* smem = (char*)smem4;
    int t = threadIdx.x;
    int p = blockIdx.x;
    int vi = (p & 7) * 768 + (p >> 3);    // xcd-contiguous remap (6144 blocks)
    int m = vi >> 11;
    int n0 = (vi & 2047) << 5;
    const unsigned char* xl8 = XL8in + (size_t)m * NC;
    unsigned char* xlo = XL8out + (size_t)m * NC;
    __hip_bfloat16* xrb = XRb + (size_t)m * NC;
    // ---- GAT phase ----
    int cbase = off[n0];
    int cc = min(off[n0 + 32] - cbase, 384);
    for (int i = t; i < cc; i += 128) csr_c[i] = csr[cbase + i];
    __syncthreads();
    int g16 = t >> 4;                      // group 0..7, 4 nodes each
    int c4 = (t & 15) << 2;
    const float* at = gatt + m * 192;
    const float* bb = gb + m * 192;
    const float LOG2E = 1.44269504089f;
    f32x4 a4 = *(const f32x4*)(at + c4);
    f32x2 a01 = {a4[0] * LOG2E, a4[1] * LOG2E};
    f32x2 a23 = {a4[2] * LOG2E, a4[3] * LOG2E};
    f32x4 b4 = *(const f32x4*)(bb + c4);
    uint2v* lau = (uint2v*)smem;
    int cchunk = c4 >> 3, half = (c4 >> 2) & 1;
    const int* bp = bperm + n0;
#pragma unroll
    for (int nn = 0; nn < 4; ++nn) {
        int rank = (nn & 1) ? (nn * 8 + (7 - g16)) : (nn * 8 + g16);  // snake
        int r = bp[rank];                  // node-local row 0..31 (sorted order)
        int n = n0 + r;
        uint2v o = gat_node(xl8, xrb, csr, csr_c, cbase, cc, n,
                            off[n], off[n + 1], c4, a01, a23, b4);
        lau[(r * 8 + (cchunk ^ (r & 7))) * 2 + half] = o;   // bf16 into mm A-tile
    }
    __syncthreads();
    // ---- MM phase (layer l+1) ----
    mm_phase32(smem, t, pw + m * 24576, xlo, xrb, n0);
}

// ---------------- k_gatfin: final GAT layer -> branch buffers, 3 modules ----------------
__global__ __launch_bounds__(256) void k_gatfin(const unsigned char* __restrict__ XL8,
        const __hip_bfloat16* __restrict__ XRb, const float* __restrict__ gatt,
        const float* __restrict__ gb, const int* __restrict__ off,
        const int* __restrict__ csr, __hip_bfloat16* __restrict__ brs,
        const int* __restrict__ bperm) {
    __shared__ int csr_c[320];
    int t = threadIdx.x, lane = t & 63;
    int p = blockIdx.x;
    int vi = (p & 7) * 768 + (p >> 3);     // xcd-contiguous remap (6144 blocks)
    int m = vi >> 11;
    int nblk = (vi & 2047) * 32;
    const unsigned char* xl8 = XL8 + (size_t)m * NC;
    const __hip_bfloat16* xrb = XRb + (size_t)m * NC;
    __hip_bfloat16* outb = brs + (size_t)m * NC;
    int cbase = off[nblk];
    int cc = min(off[nblk + 32] - cbase, 320);
    for (int i = t; i < cc; i += 256) csr_c[i] = csr[cbase + i];
    __syncthreads();
    int g = (lane >> 4) & 3;
    int gg = (t >> 6) * 4 + g;             // group 0..15, 2 nodes each
    int c4 = (lane & 15) << 2;
    const float* at = gatt + m * 192;
    const float* bb = gb + m * 192;
    const float LOG2E = 1.44269504089f;
    f32x4 a4 = *(const f32x4*)(at + c4);
    f32x2 a01 = {a4[0] * LOG2E, a4[1] * LOG2E};
    f32x2 a23 = {a4[2] * LOG2E, a4[3] * LOG2E};
    f32x4 b4 = *(const f32x4*)(bb + c4);
    const int* bp = bperm + nblk;
#pragma unroll
    for (int nn = 0; nn < 2; ++nn) {
        int rank = (nn & 1) ? (16 + (15 - gg)) : gg;   // snake
        int n = nblk + bp[rank];
        uint2v o = gat_node(xl8, xrb, csr, csr_c, cbase, cc, n,
                            off[n], off[n + 1], c4, a01, a23, b4);
        *(uint2v*)(outb + (size_t)n * 64 + c4) = o;
    }
}

// ---------------- 1x1 conv (MFMA): out = cat(b0,b1,b2)@W + bias + res ----------------
__global__ __launch_bounds__(256) void k_cc2(const __hip_bfloat16* __restrict__ b0,
        const __hip_bfloat16* __restrict__ b1, const __hip_bfloat16* __restrict__ b2,
        const __hip_bfloat16* __restrict__ pw, const float* __restrict__ bias,
        const float* __restrict__ resin, float* __restrict__ imgout,
        __hip_bfloat16* __restrict__ outb) {
    __shared__ i32x4 la[128 * 8];
    int t = threadIdx.x, lane = t & 63, wid = t >> 6;
    int n0 = blockIdx.x * 128;
    const __hip_bfloat16* brs[3] = {b0, b1, b2};
    const i32x4* wp4 = (const i32x4*)pw;
    f32x4 acc[2][4];
#pragma unroll
    for (int mi = 0; mi < 2; ++mi)
#pragma unroll
        for (int nt = 0; nt < 4; ++nt) acc[mi][nt] = (f32x4)0.0f;
#pragma unroll
    for (int br = 0; br < 3; ++br) {
        __syncthreads();
        const i32x4* Bg = (const i32x4*)brs[br] + n0 * 8;
        for (int idx = t; idx < 1024; idx += 256) {
            int r = idx >> 3, c = idx & 7;
            la[r * 8 + (c ^ (r & 7))] = Bg[idx];
        }
        __syncthreads();
        bf16x8 bf[4][2];
#pragma unroll
        for (int nt = 0; nt < 4; ++nt)
#pragma unroll
            for (int kk = 0; kk < 2; ++kk)
                bf[nt][kk] = __builtin_bit_cast(bf16x8,
                    wp4[(br * 8 + nt * 2 + kk) * 64 + lane]);
#pragma unroll
        for (int mi = 0; mi < 2; ++mi) {
            int row = wid * 32 + mi * 16 + (lane & 15);
#pragma unroll
            for (int kk = 0; kk < 2; ++kk) {
                bf16x8 a = __builtin_bit_cast(bf16x8,
                    la[row * 8 + (((kk << 2) | (lane >> 4)) ^ (row & 7))]);
#pragma unroll
                for (int nt = 0; nt < 4; ++nt)
                    acc[mi][nt] = mfma16(a, bf[nt][kk], acc[mi][nt]);
            }
        }
    }
#pragma unroll
    for (int mi = 0; mi < 2; ++mi)
#pragma unroll
        for (int nt = 0; nt < 4; ++nt) {
            int co = nt * 16 + (lane & 15);
            float bv = bias[co];
#pragma unroll
            for (int r = 0; r < 4; ++r) {
                int node = n0 + wid * 32 + mi * 16 + (lane >> 4) * 4 + r;
                float v = acc[mi][nt][r] + bv + resin[node * 64 + co];
                imgout[node * 64 + co] = v;
                outb[node * 64 + co] = __float2bfloat16(v);
            }
        }
}

// final stage: same GEMM, output NCHW fp32 via LDS transpose
__global__ __launch_bounds__(256) void k_ccfin(const __hip_bfloat16* __restrict__ b0,
        const __hip_bfloat16* __restrict__ b1, const __hip_bfloat16* __restrict__ b2,
        const __hip_bfloat16* __restrict__ pw, const float* __restrict__ bias,
        const float* __restrict__ resin, float* __restrict__ outp) {
    __shared__ i32x4 la[128 * 8];
    __shared__ float tt[64][132];
    int t = threadIdx.x, lane = t & 63, wid = t >> 6;
    int n0 = blockIdx.x * 128;
    const __hip_bfloat16* brs[3] = {b0, b1, b2};
    const i32x4* wp4 = (const i32x4*)pw;
    f32x4 acc[2][4];
#pragma unroll
    for (int mi = 0; mi < 2; ++mi)
#pragma unroll
        for (int nt = 0; nt < 4; ++nt) acc[mi][nt] = (f32x4)0.0f;
#pragma unroll
    for (int br = 0; br < 3; ++br) {
        __syncthreads();
        const i32x4* Bg = (const i32x4*)brs[br] + n0 * 8;
        for (int idx = t; idx < 1024; idx += 256) {
            int r = idx >> 3, c = idx & 7;
            la[r * 8 + (c ^ (r & 7))] = Bg[idx];
        }
        __syncthreads();
        bf16x8 bf[4][2];
#pragma unroll
        for (int nt = 0; nt < 4; ++nt)
#pragma unroll
            for (int kk = 0; kk < 2; ++kk)
                bf[nt][kk] = __builtin_bit_cast(bf16x8,
                    wp4[(br * 8 + nt * 2 + kk) * 64 + lane]);
#pragma unroll
        for (int mi = 0; mi < 2; ++mi) {
            int row = wid * 32 + mi * 16 + (lane & 15);
#pragma unroll
            for (int kk = 0; kk < 2; ++kk) {
                bf16x8 a = __builtin_bit_cast(bf16x8,
                    la[row * 8 + (((kk << 2) | (lane >> 4)) ^ (row & 7))]);
#pragma unroll
                for (int nt = 0; nt < 4; ++nt)
                    acc[mi][nt] = mfma16(a, bf[nt][kk], acc[mi][nt]);
            }
        }
    }
#pragma unroll
    for (int mi = 0; mi < 2; ++mi)
#pragma unroll
        for (int nt = 0; nt < 4; ++nt) {
            int co = nt * 16 + (lane & 15);
            float bv = bias[co];
#pragma unroll
            for (int r = 0; r < 4; ++r) {
                int nl = wid * 32 + mi * 16 + (lane >> 4) * 4 + r;
                tt[co][nl] = acc[mi][nt][r] + bv + resin[(n0 + nl) * 64 + co];
            }
        }
    __syncthreads();
    for (int u = t; u < 2048; u += 256) {
        int row = u >> 5;
        int col = (u & 31) * 4;
        f32x4 v = *(const f32x4*)&tt[row][col];
        *(f32x4*)(outp + row * HW + n0 + col) = v;
    }
}

// ---------------- 3x3 conv 64->64, channels-last, MFMA, 64-pixel blocks ----------------
template <int MODE>
__global__ __launch_bounds__(256) void k_conv(const __hip_bfloat16* __restrict__ inb,
        const __hip_bfloat16* __restrict__ wp, const float* __restrict__ bias,
        const float* __restrict__ pa, float* __restrict__ img,
        __hip_bfloat16* __restrict__ outb) {
    __shared__ i32x4 la[2][66 * 8];
    int t = threadIdx.x, lane = t & 63, wid = t >> 6;
    int y = blockIdx.x >> 2, x0 = (blockIdx.x & 3) << 6;
    f32x4 acc[4];
#pragma unroll
    for (int nt = 0; nt < 4; ++nt) acc[nt] = (f32x4)0.0f;
    const i32x4* ing = (const i32x4*)inb;
    auto stage = [&](int dy, int buf) {
        int sy = y + dy - 1;
        bool rowok = (sy >= 0) && (sy < 256);
        for (int idx = t; idx < 528; idx += 256) {
            int r = idx >> 3, c = idx & 7;
            int sx = x0 - 1 + r;
            i32x4 v = (i32x4)0;
            if (rowok && sx >= 0 && sx < 256) v = ing[(sy * 256 + sx) * 8 + c];
            la[buf][r * 8 + (c ^ (r & 7))] = v;
        }
    };
    stage(0, 0);
    __syncthreads();
#pragma unroll
    for (int dy = 0; dy < 3; ++dy) {
        if (dy < 2) stage(dy + 1, (dy + 1) & 1);
        const i32x4* lb = la[dy & 1];
#pragma unroll
        for (int dx = 0; dx < 3; ++dx) {
            const i32x4* wpt = (const i32x4*)wp + (dy * 3 + dx) * 512 + lane;
            bf16x8 b[4][2];
#pragma unroll
            for (int nt = 0; nt < 4; ++nt)
#pragma unroll
                for (int kk = 0; kk < 2; ++kk)
                    b[nt][kk] = __builtin_bit_cast(bf16x8, wpt[(nt * 2 + kk) * 64]);
            int row = dx + wid * 16 + (lane & 15);
#pragma unroll
            for (int kk = 0; kk < 2; ++kk) {
                bf16x8 a = __builtin_bit_cast(bf16x8,
                    lb[row * 8 + (((kk << 2) | (lane >> 4)) ^ (row & 7))]);
#pragma unroll
                for (int nt = 0; nt < 4; ++nt)
                    acc[nt] = mfma16(a, b[nt][kk], acc[nt]);
            }
        }
        __syncthreads();
    }
    int pbase = y * 256 + x0 + wid * 16 + (lane >> 4) * 4;
    float aprelu = (MODE == 0) ? pa[0] : 0.f;
#pragma unroll
    for (int nt = 0; nt < 4; ++nt) {
        int co = nt * 16 + (lane & 15);
        float bv = bias[co];
#pragma unroll
        for (int r = 0; r < 4; ++r) {
            int pix = pbase + r;
            float v = acc[nt][r] + bv;
            if (MODE == 0) {
                v = v >= 0.f ? v : aprelu * v;
                outb[pix * 64 + co] = __float2bfloat16(v);
            } else {
                v += img[pix * 64 + co];
                img[pix * 64 + co] = v;
                outb[pix * 64 + co] = __float2bfloat16(v);
            }
        }
    }
}

// ---------------- host ----------------
extern "C" void kernel_launch(void* const* d_in, const int* in_sizes, int n_in,
                              void* d_out, int out_size, void* d_ws, size_t ws_size,
                              hipStream_t stream) {
    const float* x    = (const float*)d_in[0];
    const int*   ei   = (const int*)d_in[1];
    const float* gWl  = (const float*)d_in[2];   // [27][64][64]
    const float* gWr  = (const float*)d_in[3];
    const float* gatt = (const float*)d_in[4];   // [27][64]
    const float* gb   = (const float*)d_in[5];   // [27][64]
    const float* ccw  = (const float*)d_in[6];   // [3][64][192]
    const float* ccb  = (const float*)d_in[7];   // [3][64]
    const float* rbw  = (const float*)d_in[8];   // [16][64][64][3][3]
    const float* rbb  = (const float*)d_in[9];   // [16][64]
    const float* rba  = (const float*)d_in[10];  // [8]
    float* outp = (float*)d_out;

    float* wsf = (float*)d_ws;
    float* xn  = wsf;                              // NC f32
    float* img = xn + NC;                          // NC f32
    __hip_bfloat16* xrb3 = (__hip_bfloat16*)(img + NC);     // 3*NC bf16
    unsigned char* xl8p0 = (unsigned char*)(xrb3 + 3 * (size_t)NC);  // 3*NC B
    unsigned char* xl8p1 = xl8p0 + 3 * (size_t)NC;                    // 3*NC B
    __hip_bfloat16* xb   = (__hip_bfloat16*)(xl8p1 + 3 * (size_t)NC);
    __hip_bfloat16* b0b  = xb + NC;
    __hip_bfloat16* b1b  = b0b + NC;
    __hip_bfloat16* b2b  = b1b + NC;
    __hip_bfloat16* cvb  = b0b;                    // overlay: branches dead during convs
    __hip_bfloat16* wpkc = b2b + NC;               // 589824
    __hip_bfloat16* wpkm = wpkc + 589824;          // 221184
    __hip_bfloat16* ccpk = wpkm + 221184;          // 36864
    int* ioff = (int*)(ccpk + 36864);
    int* icnt = ioff + (N_NODES + 1);
    int* icur = icnt + N_NODES;
    int* icsr = icur + N_NODES;                    // NE
    int* ibperm = icsr + NE;                       // N

    const int* srcA = ei;
    const int* dstA = ei + NE;

    hipMemsetAsync(icnt, 0, N_NODES * sizeof(int), stream);
    k_hist<<<NE / 256, 256, 0, stream>>>(dstA, icnt);
    k_scan<<<1, 1024, 0, stream>>>(icnt, ioff);
    hipMemcpyAsync(icur, ioff, N_NODES * sizeof(int), hipMemcpyDeviceToDevice, stream);
    k_fill<<<NE / 256, 256, 0, stream>>>(srcA, dstA, icur, icsr);
    k_bsort<<<N_NODES / 256, 256, 0, stream>>>(ioff, ibperm);
    k_cvpack<<<2304, 256, 0, stream>>>(rbw, wpkc);
    k_mmpack<<<864, 256, 0, stream>>>(gWl, gWr, wpkm);
    k_ccpack<<<144, 256, 0, stream>>>(ccw, ccpk);
    k_init<<<1024, 256, 0, stream>>>(x, xn, xb);

    for (int st = 0; st < 3; ++st) {
        int L = st * 9;
        k_mm3<<<6144, 128, 0, stream>>>(xb, wpkm + (size_t)L * 8192, xl8p0, xrb3);
        k_fuse<<<6144, 128, 0, stream>>>(xl8p0, xl8p1, xrb3,
            gatt + L * 64, gb + L * 64, wpkm + (size_t)(L + 1) * 8192, ioff, icsr,
            ibperm);
        k_fuse<<<6144, 128, 0, stream>>>(xl8p1, xl8p0, xrb3,
            gatt + (L + 1) * 64, gb + (L + 1) * 64, wpkm + (size_t)(L + 2) * 8192,
            ioff, icsr, ibperm);
        k_gatfin<<<6144, 256, 0, stream>>>(xl8p0, xrb3,
            gatt + (L + 2) * 64, gb + (L + 2) * 64, ioff, icsr, b0b, ibperm);
        const float* resin = (st == 0) ? xn : img;
        if (st == 2) {
            k_ccfin<<<N_NODES / 128, 256, 0, stream>>>(b0b, b1b, b2b,
                ccpk + 2 * 12288, ccb + 128, resin, outp);
        } else {
            k_cc2<<<N_NODES / 128, 256, 0, stream>>>(b0b, b1b, b2b,
                ccpk + st * 12288, ccb + st * 64, resin, img, xb);
            for (int bk = 0; bk < 4; ++bk) {
                int cv = (st * 4 + bk) * 2;
                k_conv<0><<<1024, 256, 0, stream>>>(xb, wpkc + (size_t)cv * 36864,
                    rbb + cv * 64, rba + st * 4 + bk, nullptr, cvb);
                k_conv<1><<<1024, 256, 0, stream>>>(cvb, wpkc + (size_t)(cv + 1) * 36864,
                    rbb + (cv + 1) * 64, nullptr, img, xb);
            }
        }
    }
}